// Round 12
// baseline (109.225 us; speedup 1.0000x reference)
//
#include <hip/hip_runtime.h>
#include <hip/hip_bf16.h>
#include <cstdint>
#include <cstddef>

#define NG 32
#define NP 64
#define ND 512
#define HW 192
#define KS 32  // number of K=16 MFMA steps
#define EPSV 1e-5f

typedef _Float16 half8 __attribute__((ext_vector_type(8)));
typedef float floatx4 __attribute__((ext_vector_type(4)));
typedef float floatx16 __attribute__((ext_vector_type(16)));

// ---- unified pre-pass: src[b][d][x] f32 -> T[b][ks][rb][hi][l31][j] fp16
// (d = ks*16 + hi*8 + j, x = rb*32 + l31).  Fragment-ready: one 32x32x16 frag
// load = base + lane*16B, fully contiguous per wave.  Same transform for both
// operands (A row = probe-y, B row = gal-x); symmetric k-slot mapping cancels.
__global__ __launch_bounds__(256) void prep_frag(const float* __restrict__ gal,
                                                 const float* __restrict__ prob,
                                                 _Float16* __restrict__ galT4,
                                                 _Float16* __restrict__ probT4) {
  __shared__ float lds[16 * 192];
  const int z = blockIdx.x;   // 0..95: first NP probes, then NG gals
  const int ks = blockIdx.y;  // 0..31
  const float* src;
  _Float16* dst;
  if (z < NP) {
    src = prob + (size_t)z * ND * HW;
    dst = probT4 + (size_t)z * 98304;
  } else {
    src = gal + (size_t)(z - NP) * ND * HW;
    dst = galT4 + (size_t)(z - NP) * 98304;
  }
  src += (size_t)ks * 16 * HW;
  dst += (size_t)ks * 3072;
  const int t = threadIdx.x;
  // 16 rows x 192 cols are contiguous in src (row stride == HW): linear copy.
#pragma unroll
  for (int i = 0; i < 12; ++i) lds[i * 256 + t] = src[i * 256 + t];
  __syncthreads();
#pragma unroll
  for (int r = 0; r < 2; ++r) {
    const int h = r * 256 + t;  // h = rb*64 + hi*32 + l31, 384 slots
    if (h < 384) {
      const int rb = h >> 6, hi = (h >> 5) & 1, l31 = h & 31;
      half8 v;
#pragma unroll
      for (int j = 0; j < 8; ++j) v[j] = (_Float16)lds[(hi * 8 + j) * 192 + rb * 32 + l31];
      *(half8*)(dst + (size_t)h * 8) = v;
    }
  }
}

// ---- main fused kernel: one WG (256 thr, 4 waves) per (g,p) pair ----
// ZERO barriers in the K-loop: no LDS operands.  Each wave independently
// streams A (probe) and B (gal) fragments global->VGPR from the frag-ready
// tiles, register-double-buffered 2 K-steps ahead (~576 cyc lead > L2
// latency), and issues 9 independent mfma_f32_32x32x16_f16 per step.
// Wave (wr,wc) computes the 96x96 quadrant; pair-redundant loads dedup in L1.
__global__ __launch_bounds__(256, 2) void qaconv_main(
    const _Float16* __restrict__ galT4, const _Float16* __restrict__ probT4,
    const float* __restrict__ bn_w, const float* __restrict__ bn_b,
    const float* __restrict__ bn_m, const float* __restrict__ bn_v,
    const float* __restrict__ fc_w, const float* __restrict__ fc_b,
    const float* __restrict__ lbn_w, const float* __restrict__ lbn_b,
    const float* __restrict__ lbn_m, const float* __restrict__ lbn_v,
    float* __restrict__ out) {
  __shared__ float colp[2][HW];
  __shared__ float rowpart[2][HW];
  __shared__ float wsum[4];

  const int bid = blockIdx.x;
  const int g = bid >> 6, p = bid & 63;

  const int t = threadIdx.x;
  const int lane = t & 63, wid = t >> 6;
  const int wr = wid & 1;   // probe-row half (y block of 96)
  const int wc = wid >> 1;  // gal-col half (x block of 96)
  const int l31 = lane & 31, hi = lane >> 5;

  // per-lane fragment base: uniform + lane*16B (halves: lane*8)
  const _Float16* pA = probT4 + (size_t)p * 98304 + wr * 1536 + lane * 8;
  const _Float16* pB = galT4 + (size_t)g * 98304 + wc * 1536 + lane * 8;

  floatx16 acc[3][3];
#pragma unroll
  for (int ii = 0; ii < 3; ++ii)
#pragma unroll
    for (int jj = 0; jj < 3; ++jj) acc[ii][jj] = (floatx16)0.f;

#define LOADF(AF, BF, ks_)                                   \
  {                                                          \
    const _Float16* a_ = pA + (size_t)(ks_)*3072;            \
    const _Float16* b_ = pB + (size_t)(ks_)*3072;            \
    AF[0] = *(const half8*)(a_);                             \
    AF[1] = *(const half8*)(a_ + 512);                       \
    AF[2] = *(const half8*)(a_ + 1024);                      \
    BF[0] = *(const half8*)(b_);                             \
    BF[1] = *(const half8*)(b_ + 512);                       \
    BF[2] = *(const half8*)(b_ + 1024);                      \
  }

#define MFMAS(AF, BF)                                                            \
  {                                                                              \
    __builtin_amdgcn_s_setprio(1);                                               \
    _Pragma("unroll") for (int ii = 0; ii < 3; ++ii)                             \
        _Pragma("unroll") for (int jj = 0; jj < 3; ++jj)                         \
            acc[ii][jj] = __builtin_amdgcn_mfma_f32_32x32x16_f16(AF[ii], BF[jj], \
                                                                 acc[ii][jj], 0, 0, 0); \
    __builtin_amdgcn_s_setprio(0);                                               \
  }

  half8 af0[3], bf0[3], af1[3], bf1[3];
  LOADF(af0, bf0, 0)
  LOADF(af1, bf1, 1)
  for (int ks = 0; ks < KS; ks += 2) {
    const int n0 = (ks + 2 < KS) ? ks + 2 : 30;  // tail: redundant in-bounds reload
    const int n1 = (ks + 3 < KS) ? ks + 3 : 31;
    MFMAS(af0, bf0)
    LOADF(af0, bf0, n0)  // issued after af0/bf0 consumed; in flight ~1 full step
    MFMAS(af1, bf1)
    LOADF(af1, bf1, n1)
  }

  // ---- epilogue: dual-axis max (only barrier in the kernel) ----
  // C/D map: col X = wc*96 + fb*32 + l31, row Y = wr*96 + fa*32 + (e&3)+8*(e>>2)+4*hi
#pragma unroll
  for (int fb = 0; fb < 3; ++fb) {
    float v = -3.4e38f;
#pragma unroll
    for (int fa = 0; fa < 3; ++fa)
#pragma unroll
      for (int e = 0; e < 16; ++e) v = fmaxf(v, acc[fa][fb][e]);
    v = fmaxf(v, __shfl_xor(v, 32));
    if (lane < 32) colp[wr][wc * 96 + fb * 32 + lane] = v;
  }
  // rowmax: lane-local over 3 col-frags, 5-step butterfly across l31
#pragma unroll
  for (int fa = 0; fa < 3; ++fa)
#pragma unroll
    for (int e = 0; e < 16; ++e) {
      float rv = fmaxf(fmaxf(acc[fa][0][e], acc[fa][1][e]), acc[fa][2][e]);
      rv = fmaxf(rv, __shfl_xor(rv, 1));
      rv = fmaxf(rv, __shfl_xor(rv, 2));
      rv = fmaxf(rv, __shfl_xor(rv, 4));
      rv = fmaxf(rv, __shfl_xor(rv, 8));
      rv = fmaxf(rv, __shfl_xor(rv, 16));
      if (l31 == 0) {
        const int Y = wr * 96 + fa * 32 + (e & 3) + 8 * (e >> 2) + 4 * hi;
        rowpart[wc][Y] = rv;
      }
    }
  __syncthreads();

  // ---- fused BN -> fc dot -> logit BN -> sigmoid ----
  float partial = 0.f;
  if (t < HW) {
    const float rmax = fmaxf(rowpart[0][t], rowpart[1][t]);
    const float cmax = fmaxf(colp[0][t], colp[1][t]);
    const float scale = bn_w[0] / sqrtf(bn_v[0] + EPSV);
    const float bm = bn_m[0], bb = bn_b[0];
    partial = ((cmax - bm) * scale + bb) * fc_w[t] +
              ((rmax - bm) * scale + bb) * fc_w[HW + t];
  }
#pragma unroll
  for (int off = 1; off < 64; off <<= 1) partial += __shfl_xor(partial, off);
  if (lane == 0) wsum[wid] = partial;
  __syncthreads();
  if (t == 0) {
    const float sum = fc_b[0] + wsum[0] + wsum[1] + wsum[2] + wsum[3];
    const float logit = (sum - lbn_m[0]) * (lbn_w[0] / sqrtf(lbn_v[0] + EPSV)) + lbn_b[0];
    out[bid] = 1.f / (1.f + expf(-logit * 0.1f));
  }
#undef LOADF
#undef MFMAS
}

// ---------------- naive f32 fallback (only if ws too small) ----------------
__global__ __launch_bounds__(256) void qaconv_naive(
    const float* __restrict__ gal, const float* __restrict__ prob,
    const float* __restrict__ bn_w, const float* __restrict__ bn_b,
    const float* __restrict__ bn_m, const float* __restrict__ bn_v,
    const float* __restrict__ fc_w, const float* __restrict__ fc_b,
    const float* __restrict__ lbn_w, const float* __restrict__ lbn_b,
    const float* __restrict__ lbn_m, const float* __restrict__ lbn_v,
    float* __restrict__ out) {
  __shared__ float prow[ND];
  __shared__ float rowmaxs[HW];
  __shared__ float colmaxs[HW];
  __shared__ float red[4];
  const int bid = blockIdx.x;
  const int g = bid >> 6, p = bid & 63;
  const int t = threadIdx.x, lane = t & 63, wid = t >> 6;
  const float* gp = gal + (size_t)g * ND * HW;
  const float* pp = prob + (size_t)p * ND * HW;
  float colmax = -3.4e38f;
  for (int y = 0; y < HW; ++y) {
    for (int k = t; k < ND; k += 256) prow[k] = pp[(size_t)k * HW + y];
    __syncthreads();
    float sv = -3.4e38f;
    if (t < HW) {
      sv = 0.f;
      for (int k = 0; k < ND; ++k) sv = fmaf(prow[k], gp[(size_t)k * HW + t], sv);
      colmax = fmaxf(colmax, sv);
    }
    float m = sv;
#pragma unroll
    for (int off = 1; off < 64; off <<= 1) m = fmaxf(m, __shfl_xor(m, off));
    if (lane == 0) red[wid] = m;
    __syncthreads();
    if (t == 0) rowmaxs[y] = fmaxf(fmaxf(red[0], red[1]), fmaxf(red[2], red[3]));
    __syncthreads();
  }
  if (t < HW) colmaxs[t] = colmax;
  __syncthreads();
  float partial = 0.f;
  for (int j = t; j < 2 * HW; j += 256) {
    const float v = (j < HW) ? colmaxs[j] : rowmaxs[j - HW];
    const float sc = (v - bn_m[0]) * (bn_w[0] / sqrtf(bn_v[0] + EPSV)) + bn_b[0];
    partial += sc * fc_w[j];
  }
#pragma unroll
  for (int off = 1; off < 64; off <<= 1) partial += __shfl_xor(partial, off);
  if (lane == 0) red[wid] = partial;
  __syncthreads();
  if (t == 0) {
    const float sum = fc_b[0] + red[0] + red[1] + red[2] + red[3];
    const float logit = (sum - lbn_m[0]) * (lbn_w[0] / sqrtf(lbn_v[0] + EPSV)) + lbn_b[0];
    out[bid] = 1.f / (1.f + expf(-logit * 0.1f));
  }
}

extern "C" void kernel_launch(void* const* d_in, const int* in_sizes, int n_in,
                              void* d_out, int out_size, void* d_ws, size_t ws_size,
                              hipStream_t stream) {
  const float* gal = (const float*)d_in[0];
  const float* prob = (const float*)d_in[1];
  const float* bn_w = (const float*)d_in[2];
  const float* bn_b = (const float*)d_in[3];
  const float* bn_m = (const float*)d_in[4];
  const float* bn_v = (const float*)d_in[5];
  const float* fc_w = (const float*)d_in[6];
  const float* fc_b = (const float*)d_in[7];
  const float* lbn_w = (const float*)d_in[8];
  const float* lbn_b = (const float*)d_in[9];
  const float* lbn_m = (const float*)d_in[10];
  const float* lbn_v = (const float*)d_in[11];
  float* out = (float*)d_out;

  const size_t probT4_elems = (size_t)NP * 98304;  // 6.29M halves
  const size_t galT4_elems = (size_t)NG * 98304;   // 3.15M halves
  const size_t ws_needed = (probT4_elems + galT4_elems) * sizeof(_Float16);
  if (ws_size >= ws_needed) {
    _Float16* probT4 = (_Float16*)d_ws;
    _Float16* galT4 = probT4 + probT4_elems;
    prep_frag<<<dim3(NP + NG, KS), dim3(256), 0, stream>>>(gal, prob, galT4, probT4);
    qaconv_main<<<dim3(NG * NP), dim3(256), 0, stream>>>(
        galT4, probT4, bn_w, bn_b, bn_m, bn_v, fc_w, fc_b, lbn_w, lbn_b, lbn_m, lbn_v, out);
  } else {
    qaconv_naive<<<dim3(NG * NP), dim3(256), 0, stream>>>(
        gal, prob, bn_w, bn_b, bn_m, bn_v, fc_w, fc_b, lbn_w, lbn_b, lbn_m, lbn_v, out);
  }
}